// Round 1
// baseline (354.728 us; speedup 1.0000x reference)
//
#include <hip/hip_runtime.h>

// GraphAttentionLayer: out = elu( softmax_row( where(adj>0, lrelu(src_i+dst_j), 0) ) @ wh )
// wh = x@w [8192,64]; src = wh@a[:64]; dst = wh@a[64:]
//
// Strategy:
//  - adj read (268 MB) is the HBM floor (~43us). Single fused pass over adj.
//  - Static softmax shift m_i = max(0, src_i + max_j dst_j) >= true row max
//    => p = exp(v - m_i) <= 1 always; softmax shift-invariant => exact.
//    => no online rescaling; j-split partials combine by plain summation.
//  - PV via bf16 MFMA 16x16x32 (A = P tile staged in LDS w/ padded stride,
//    B = whT bf16 [64][8192] read directly from global, L2-resident).

constexpr int N_ROWS = 8192;
constexpr int F_IN   = 128;
constexpr int F_OUT  = 64;
#define LRELU_A 0.2f

constexpr int BR   = 32;     // rows per block in attention kernel
constexpr int BC   = 256;    // j-columns per tile
constexpr int PSTR = BC + 8; // padded LDS row stride (bf16 elems): 528 B -> 2-way banks only

// workspace layout (bytes)
constexpr size_t OFF_WHT  = 0;                    // 64*8192*2 = 1 MiB (bf16 bits, [f][row])
constexpr size_t OFF_SRC  = 1048576;              // 8192 f32
constexpr size_t OFF_DST  = OFF_SRC + 32768;      // 8192 f32
constexpr size_t OFF_DMAX = OFF_DST + 32768;      // 1 f32 (padded)
constexpr size_t OFF_LP   = OFF_DMAX + 256;       // S*8192 f32
constexpr size_t OFF_ACC  = OFF_LP + 8 * 32768;   // S*8192*64 f32

typedef __attribute__((ext_vector_type(4))) float f32x4;
typedef __attribute__((ext_vector_type(4))) int   i32x4;
typedef __attribute__((ext_vector_type(4))) short s16x4;
typedef __attribute__((ext_vector_type(8))) short s16x8;

static __device__ __forceinline__ short f2bf(float f) {
  unsigned u = __float_as_uint(f);
  u = (u + 0x7fffu + ((u >> 16) & 1u)) >> 16;  // RNE, no NaN inputs here
  return (short)u;
}

// ---------------- Kernel 1: wh = x@w ; src/dst ; whT (bf16) ----------------
__global__ __launch_bounds__(256) void k1_proj(
    const float* __restrict__ x, const float* __restrict__ w,
    const float* __restrict__ a, short* __restrict__ whT,
    float* __restrict__ src, float* __restrict__ dst)
{
  const int lane = threadIdx.x & 63;   // = output feature f
  const int wid  = threadIdx.x >> 6;
  const int rowBase = blockIdx.x * 64 + wid * 16;  // 16 rows per wave

  float acc[16];
#pragma unroll
  for (int r = 0; r < 16; ++r) acc[r] = 0.0f;

#pragma unroll
  for (int kc = 0; kc < 4; ++kc) {     // K chunks of 32 (keeps VGPR bounded)
    float wreg[32];
#pragma unroll
    for (int kk = 0; kk < 32; ++kk)
      wreg[kk] = w[(kc * 32 + kk) * F_OUT + lane];   // coalesced
#pragma unroll
    for (int r = 0; r < 16; ++r) {
      const f32x4* xp = (const f32x4*)(x + (size_t)(rowBase + r) * F_IN + kc * 32);
#pragma unroll
      for (int q = 0; q < 8; ++q) {    // wave-uniform broadcast loads
        f32x4 xv = xp[q];
        acc[r] = fmaf(xv.x, wreg[4*q+0], acc[r]);
        acc[r] = fmaf(xv.y, wreg[4*q+1], acc[r]);
        acc[r] = fmaf(xv.z, wreg[4*q+2], acc[r]);
        acc[r] = fmaf(xv.w, wreg[4*q+3], acc[r]);
      }
    }
  }

  const float aS = a[lane];
  const float aD = a[F_OUT + lane];
#pragma unroll
  for (int r = 0; r < 16; ++r) {
    const int row = rowBase + r;
    const float wh = acc[r];
    whT[(size_t)lane * N_ROWS + row] = f2bf(wh);
    float ts = wh * aS;
    float td = wh * aD;
#pragma unroll
    for (int off = 32; off > 0; off >>= 1) {
      ts += __shfl_xor(ts, off, 64);
      td += __shfl_xor(td, off, 64);
    }
    if (lane == 0) { src[row] = ts; dst[row] = td; }
  }
}

// ---------------- Kernel 1b: dstmax ----------------
__global__ __launch_bounds__(256) void k1b_dstmax(
    const float* __restrict__ dst, float* __restrict__ dmax)
{
  float m = -1e30f;
  for (int i = threadIdx.x; i < N_ROWS; i += 256) m = fmaxf(m, dst[i]);
#pragma unroll
  for (int off = 32; off > 0; off >>= 1) m = fmaxf(m, __shfl_xor(m, off, 64));
  __shared__ float sm[4];
  if ((threadIdx.x & 63) == 0) sm[threadIdx.x >> 6] = m;
  __syncthreads();
  if (threadIdx.x == 0)
    dmax[0] = fmaxf(fmaxf(sm[0], sm[1]), fmaxf(sm[2], sm[3]));
}

// ---------------- Kernel 2: fused mask+softmax-numerator+PV ----------------
// grid: (N/BR row-blocks, S j-splits), 256 threads (4 waves)
__global__ __launch_bounds__(256) void k2_attn(
    const int* __restrict__ adj, const short* __restrict__ whT,
    const float* __restrict__ src, const float* __restrict__ dst,
    const float* __restrict__ dmaxp, float* __restrict__ acc_part,
    float* __restrict__ l_part, int S)
{
  __shared__ short Plds[BR * PSTR];

  const int lane = threadIdx.x & 63;
  const int wid  = threadIdx.x >> 6;
  const int rb   = blockIdx.x;
  const int s    = blockIdx.y;
  const int jlen = N_ROWS / S;
  const int jbase = s * jlen;
  const int ntiles = jlen / BC;
  const float dmax = dmaxp[0];

  // phase-A rows for this wave: wid*8 .. wid*8+7
  float srcv[8], mrow[8], lp[8];
#pragma unroll
  for (int r = 0; r < 8; ++r) {
    srcv[r] = src[rb * BR + wid * 8 + r];
    mrow[r] = fmaxf(0.0f, srcv[r] + dmax);  // static upper bound on row max
    lp[r]   = 0.0f;
  }

  // MFMA tile ownership: Mtile = wid&1, Ntiles = 2*(wid>>1)+{0,1}
  const int mt  = wid & 1;
  const int nt0 = (wid >> 1) * 2;
  f32x4 accA = {0.f, 0.f, 0.f, 0.f};
  f32x4 accB = {0.f, 0.f, 0.f, 0.f};

  for (int t = 0; t < ntiles; ++t) {
    const int j0 = jbase + t * BC;
    const f32x4 d4 = *(const f32x4*)(dst + j0 + 4 * lane);

    // ---- phase A: p = exp(v - m), pack bf16 into LDS ----
#pragma unroll
    for (int r = 0; r < 8; ++r) {
      const int row = rb * BR + wid * 8 + r;
      const i32x4 av = *(const i32x4*)(adj + (size_t)row * N_ROWS + j0 + 4 * lane);
      const float m = mrow[r];
      const float sv = srcv[r];
      float e0 = sv + d4.x; e0 = e0 > 0.f ? e0 : LRELU_A * e0; e0 = av.x > 0 ? e0 : 0.f;
      float e1 = sv + d4.y; e1 = e1 > 0.f ? e1 : LRELU_A * e1; e1 = av.y > 0 ? e1 : 0.f;
      float e2 = sv + d4.z; e2 = e2 > 0.f ? e2 : LRELU_A * e2; e2 = av.z > 0 ? e2 : 0.f;
      float e3 = sv + d4.w; e3 = e3 > 0.f ? e3 : LRELU_A * e3; e3 = av.w > 0 ? e3 : 0.f;
      const float p0 = __expf(e0 - m);
      const float p1 = __expf(e1 - m);
      const float p2 = __expf(e2 - m);
      const float p3 = __expf(e3 - m);
      lp[r] += (p0 + p1) + (p2 + p3);
      s16x4 pk; pk.x = f2bf(p0); pk.y = f2bf(p1); pk.z = f2bf(p2); pk.w = f2bf(p3);
      *(s16x4*)&Plds[(wid * 8 + r) * PSTR + 4 * lane] = pk;
    }
    __syncthreads();

    // ---- phase B: PV MFMA ----
#pragma unroll
    for (int k = 0; k < BC / 32; ++k) {
      const s16x8 afr = *(const s16x8*)&Plds[(mt * 16 + (lane & 15)) * PSTR
                                             + k * 32 + (lane >> 4) * 8];
      const short* bp = whT + (size_t)(nt0 * 16 + (lane & 15)) * N_ROWS
                        + j0 + k * 32 + (lane >> 4) * 8;
      const s16x8 bf0 = *(const s16x8*)bp;
      const s16x8 bf1 = *(const s16x8*)(bp + (size_t)16 * N_ROWS);
      accA = __builtin_amdgcn_mfma_f32_16x16x32_bf16(afr, bf0, accA, 0, 0, 0);
      accB = __builtin_amdgcn_mfma_f32_16x16x32_bf16(afr, bf1, accB, 0, 0, 0);
    }
    __syncthreads();
  }

  // ---- epilogue: row-sum partials + accumulator store ----
#pragma unroll
  for (int r = 0; r < 8; ++r) {
    float v = lp[r];
#pragma unroll
    for (int off = 32; off > 0; off >>= 1) v += __shfl_xor(v, off, 64);
    if (lane == 0) l_part[(size_t)s * N_ROWS + rb * BR + wid * 8 + r] = v;
  }
#pragma unroll
  for (int rg = 0; rg < 4; ++rg) {
    // verified C/D layout: col = lane&15, row = (lane>>4)*4 + reg
    const int row = rb * BR + mt * 16 + (lane >> 4) * 4 + rg;
    const int f0  = nt0 * 16 + (lane & 15);
    acc_part[((size_t)s * N_ROWS + row) * F_OUT + f0]      = accA[rg];
    acc_part[((size_t)s * N_ROWS + row) * F_OUT + f0 + 16] = accB[rg];
  }
}

// ---------------- Kernel 3: combine partials, normalize, ELU ----------------
__global__ __launch_bounds__(256) void k3_combine(
    const float* __restrict__ acc_part, const float* __restrict__ l_part,
    float* __restrict__ out, int S)
{
  const int idx = blockIdx.x * 256 + threadIdx.x;  // over N*F/4
  const int row = idx >> 4;          // F_OUT/4 = 16
  const int f4  = idx & 15;
  f32x4 h = {0.f, 0.f, 0.f, 0.f};
  float l = 0.f;
  for (int s = 0; s < S; ++s) {
    h += *(const f32x4*)(acc_part + ((size_t)s * N_ROWS + row) * F_OUT + 4 * f4);
    l += l_part[(size_t)s * N_ROWS + row];
  }
  const float inv = 1.0f / l;
  f32x4 o;
  {
    float v0 = h.x * inv; o.x = v0 > 0.f ? v0 : (__expf(v0) - 1.0f);
    float v1 = h.y * inv; o.y = v1 > 0.f ? v1 : (__expf(v1) - 1.0f);
    float v2 = h.z * inv; o.z = v2 > 0.f ? v2 : (__expf(v2) - 1.0f);
    float v3 = h.w * inv; o.w = v3 > 0.f ? v3 : (__expf(v3) - 1.0f);
  }
  *(f32x4*)(out + (size_t)row * F_OUT + 4 * f4) = o;
}

// ---------------- launch ----------------
extern "C" void kernel_launch(void* const* d_in, const int* in_sizes, int n_in,
                              void* d_out, int out_size, void* d_ws, size_t ws_size,
                              hipStream_t stream) {
  const float* x   = (const float*)d_in[0];
  const int*   adj = (const int*)d_in[1];
  const float* w   = (const float*)d_in[2];
  const float* a   = (const float*)d_in[3];
  float* out = (float*)d_out;
  char* ws = (char*)d_ws;

  short* whT      = (short*)(ws + OFF_WHT);
  float* src      = (float*)(ws + OFF_SRC);
  float* dst      = (float*)(ws + OFF_DST);
  float* dmax     = (float*)(ws + OFF_DMAX);
  float* l_part   = (float*)(ws + OFF_LP);
  float* acc_part = (float*)(ws + OFF_ACC);

  // j-split count chosen from available workspace (deterministic)
  int S = 1;
  if (ws_size >= OFF_ACC + 4ull * 2097152) S = 4;
  else if (ws_size >= OFF_ACC + 2ull * 2097152) S = 2;

  k1_proj<<<N_ROWS / 64, 256, 0, stream>>>(x, w, a, whT, src, dst);
  k1b_dstmax<<<1, 256, 0, stream>>>(dst, dmax);
  k2_attn<<<dim3(N_ROWS / BR, S), 256, 0, stream>>>(adj, whT, src, dst, dmax,
                                                    acc_part, l_part, S);
  k3_combine<<<(N_ROWS * F_OUT / 4) / 256, 256, 0, stream>>>(acc_part, l_part, out, S);
}

// Round 2
// 124.292 us; speedup vs baseline: 2.8540x; 2.8540x over previous
//
#include <hip/hip_runtime.h>

// GraphAttentionLayer: out = elu( softmax_row( where(adj>0, lrelu(src_i+dst_j), 0) ) @ wh )
// wh = x@w [8192,64]; src = wh@a[:64]; dst = wh@a[64:]
//
// Strategy:
//  - adj read (268 MB) is the HBM floor (~43us). Single fused pass over adj.
//  - Static softmax shift m_i = max(0, src_i + max_j dst_j) >= true row max
//    => p = exp(v - m_i) <= 1 always; softmax shift-invariant => exact.
//    => no online rescaling; j-split partials combine by plain summation.
//  - PV via bf16 MFMA 16x16x32 (A = P tile staged in LDS w/ padded stride,
//    B = whT bf16 [64][8192] read directly from global, L2-resident).
//
// R1 fix: k1_proj had #pragma unroll on the K-chunk loop -> 4x wreg[32] live
// -> 256 VGPRs -> scratch spills (205 MB HBM writes, 265us). Now: 8 rows/wave,
// unroll 1 on K chunks, s16x8 packed whT store. Expect ~70 VGPR, ~6us.

constexpr int N_ROWS = 8192;
constexpr int F_IN   = 128;
constexpr int F_OUT  = 64;
#define LRELU_A 0.2f

constexpr int BR   = 32;     // rows per block in attention kernel
constexpr int BC   = 256;    // j-columns per tile
constexpr int PSTR = BC + 8; // padded LDS row stride (bf16 elems)

// workspace layout (bytes)
constexpr size_t OFF_WHT  = 0;                    // 64*8192*2 = 1 MiB (bf16 bits, [f][row])
constexpr size_t OFF_SRC  = 1048576;              // 8192 f32
constexpr size_t OFF_DST  = OFF_SRC + 32768;      // 8192 f32
constexpr size_t OFF_DMAX = OFF_DST + 32768;      // 1 f32 (padded)
constexpr size_t OFF_LP   = OFF_DMAX + 256;       // S*8192 f32
constexpr size_t OFF_ACC  = OFF_LP + 8 * 32768;   // S*8192*64 f32

typedef __attribute__((ext_vector_type(4))) float f32x4;
typedef __attribute__((ext_vector_type(4))) int   i32x4;
typedef __attribute__((ext_vector_type(4))) short s16x4;
typedef __attribute__((ext_vector_type(8))) short s16x8;

static __device__ __forceinline__ short f2bf(float f) {
  unsigned u = __float_as_uint(f);
  u = (u + 0x7fffu + ((u >> 16) & 1u)) >> 16;  // RNE, no NaN inputs here
  return (short)u;
}

// ---------------- Kernel 1: wh = x@w ; src/dst ; whT (bf16) ----------------
// 256 blocks x 256 threads; wave = 8 rows; lane = output feature.
__global__ __launch_bounds__(256) void k1_proj(
    const float* __restrict__ x, const float* __restrict__ w,
    const float* __restrict__ a, short* __restrict__ whT,
    float* __restrict__ src, float* __restrict__ dst)
{
  const int lane = threadIdx.x & 63;   // = output feature f
  const int wid  = threadIdx.x >> 6;
  const int rowBase = blockIdx.x * 32 + wid * 8;   // 8 rows per wave

  float acc[8];
#pragma unroll
  for (int r = 0; r < 8; ++r) acc[r] = 0.0f;

#pragma unroll 1
  for (int kc = 0; kc < 4; ++kc) {     // K chunks of 32 — keep ONE wreg live
    float wreg[32];
#pragma unroll
    for (int kk = 0; kk < 32; ++kk)
      wreg[kk] = w[(kc * 32 + kk) * F_OUT + lane];   // coalesced
#pragma unroll
    for (int r = 0; r < 8; ++r) {
      const f32x4* xp = (const f32x4*)(x + (size_t)(rowBase + r) * F_IN + kc * 32);
#pragma unroll
      for (int q = 0; q < 8; ++q) {    // wave-uniform broadcast loads
        f32x4 xv = xp[q];
        acc[r] = fmaf(xv.x, wreg[4*q+0], acc[r]);
        acc[r] = fmaf(xv.y, wreg[4*q+1], acc[r]);
        acc[r] = fmaf(xv.z, wreg[4*q+2], acc[r]);
        acc[r] = fmaf(xv.w, wreg[4*q+3], acc[r]);
      }
    }
  }

  // whT store: lane f's 8 consecutive rows -> one 16B packed store
  s16x8 hb;
#pragma unroll
  for (int r = 0; r < 8; ++r) hb[r] = f2bf(acc[r]);
  *(s16x8*)&whT[(size_t)lane * N_ROWS + rowBase] = hb;

  const float aS = a[lane];
  const float aD = a[F_OUT + lane];
#pragma unroll
  for (int r = 0; r < 8; ++r) {
    float ts = acc[r] * aS;
    float td = acc[r] * aD;
#pragma unroll
    for (int off = 32; off > 0; off >>= 1) {
      ts += __shfl_xor(ts, off, 64);
      td += __shfl_xor(td, off, 64);
    }
    if (lane == 0) { src[rowBase + r] = ts; dst[rowBase + r] = td; }
  }
}

// ---------------- Kernel 1b: dstmax ----------------
__global__ __launch_bounds__(256) void k1b_dstmax(
    const float* __restrict__ dst, float* __restrict__ dmax)
{
  float m = -1e30f;
  for (int i = threadIdx.x; i < N_ROWS; i += 256) m = fmaxf(m, dst[i]);
#pragma unroll
  for (int off = 32; off > 0; off >>= 1) m = fmaxf(m, __shfl_xor(m, off, 64));
  __shared__ float sm[4];
  if ((threadIdx.x & 63) == 0) sm[threadIdx.x >> 6] = m;
  __syncthreads();
  if (threadIdx.x == 0)
    dmax[0] = fmaxf(fmaxf(sm[0], sm[1]), fmaxf(sm[2], sm[3]));
}

// ---------------- Kernel 2: fused mask+softmax-numerator+PV ----------------
// grid: (N/BR row-blocks, S j-splits), 256 threads (4 waves)
__global__ __launch_bounds__(256) void k2_attn(
    const int* __restrict__ adj, const short* __restrict__ whT,
    const float* __restrict__ src, const float* __restrict__ dst,
    const float* __restrict__ dmaxp, float* __restrict__ acc_part,
    float* __restrict__ l_part, int S)
{
  __shared__ short Plds[BR * PSTR];

  const int lane = threadIdx.x & 63;
  const int wid  = threadIdx.x >> 6;
  const int rb   = blockIdx.x;
  const int s    = blockIdx.y;
  const int jlen = N_ROWS / S;
  const int jbase = s * jlen;
  const int ntiles = jlen / BC;
  const float dmax = dmaxp[0];

  // phase-A rows for this wave: wid*8 .. wid*8+7
  float srcv[8], mrow[8], lp[8];
#pragma unroll
  for (int r = 0; r < 8; ++r) {
    srcv[r] = src[rb * BR + wid * 8 + r];
    mrow[r] = fmaxf(0.0f, srcv[r] + dmax);  // static upper bound on row max
    lp[r]   = 0.0f;
  }

  // MFMA tile ownership: Mtile = wid&1, Ntiles = 2*(wid>>1)+{0,1}
  const int mt  = wid & 1;
  const int nt0 = (wid >> 1) * 2;
  f32x4 accA = {0.f, 0.f, 0.f, 0.f};
  f32x4 accB = {0.f, 0.f, 0.f, 0.f};

  for (int t = 0; t < ntiles; ++t) {
    const int j0 = jbase + t * BC;
    const f32x4 d4 = *(const f32x4*)(dst + j0 + 4 * lane);

    // ---- phase A: p = exp(v - m), pack bf16 into LDS ----
#pragma unroll
    for (int r = 0; r < 8; ++r) {
      const int row = rb * BR + wid * 8 + r;
      const i32x4 av = *(const i32x4*)(adj + (size_t)row * N_ROWS + j0 + 4 * lane);
      const float m = mrow[r];
      const float sv = srcv[r];
      float e0 = sv + d4.x; e0 = e0 > 0.f ? e0 : LRELU_A * e0; e0 = av.x > 0 ? e0 : 0.f;
      float e1 = sv + d4.y; e1 = e1 > 0.f ? e1 : LRELU_A * e1; e1 = av.y > 0 ? e1 : 0.f;
      float e2 = sv + d4.z; e2 = e2 > 0.f ? e2 : LRELU_A * e2; e2 = av.z > 0 ? e2 : 0.f;
      float e3 = sv + d4.w; e3 = e3 > 0.f ? e3 : LRELU_A * e3; e3 = av.w > 0 ? e3 : 0.f;
      const float p0 = __expf(e0 - m);
      const float p1 = __expf(e1 - m);
      const float p2 = __expf(e2 - m);
      const float p3 = __expf(e3 - m);
      lp[r] += (p0 + p1) + (p2 + p3);
      s16x4 pk; pk.x = f2bf(p0); pk.y = f2bf(p1); pk.z = f2bf(p2); pk.w = f2bf(p3);
      *(s16x4*)&Plds[(wid * 8 + r) * PSTR + 4 * lane] = pk;
    }
    __syncthreads();

    // ---- phase B: PV MFMA ----
#pragma unroll
    for (int k = 0; k < BC / 32; ++k) {
      const s16x8 afr = *(const s16x8*)&Plds[(mt * 16 + (lane & 15)) * PSTR
                                             + k * 32 + (lane >> 4) * 8];
      const short* bp = whT + (size_t)(nt0 * 16 + (lane & 15)) * N_ROWS
                        + j0 + k * 32 + (lane >> 4) * 8;
      const s16x8 bf0 = *(const s16x8*)bp;
      const s16x8 bf1 = *(const s16x8*)(bp + (size_t)16 * N_ROWS);
      accA = __builtin_amdgcn_mfma_f32_16x16x32_bf16(afr, bf0, accA, 0, 0, 0);
      accB = __builtin_amdgcn_mfma_f32_16x16x32_bf16(afr, bf1, accB, 0, 0, 0);
    }
    __syncthreads();
  }

  // ---- epilogue: row-sum partials + accumulator store ----
#pragma unroll
  for (int r = 0; r < 8; ++r) {
    float v = lp[r];
#pragma unroll
    for (int off = 32; off > 0; off >>= 1) v += __shfl_xor(v, off, 64);
    if (lane == 0) l_part[(size_t)s * N_ROWS + rb * BR + wid * 8 + r] = v;
  }
#pragma unroll
  for (int rg = 0; rg < 4; ++rg) {
    // verified C/D layout: col = lane&15, row = (lane>>4)*4 + reg
    const int row = rb * BR + mt * 16 + (lane >> 4) * 4 + rg;
    const int f0  = nt0 * 16 + (lane & 15);
    acc_part[((size_t)s * N_ROWS + row) * F_OUT + f0]      = accA[rg];
    acc_part[((size_t)s * N_ROWS + row) * F_OUT + f0 + 16] = accB[rg];
  }
}

// ---------------- Kernel 3: combine partials, normalize, ELU ----------------
__global__ __launch_bounds__(256) void k3_combine(
    const float* __restrict__ acc_part, const float* __restrict__ l_part,
    float* __restrict__ out, int S)
{
  const int idx = blockIdx.x * 256 + threadIdx.x;  // over N*F/4
  const int row = idx >> 4;          // F_OUT/4 = 16
  const int f4  = idx & 15;
  f32x4 h = {0.f, 0.f, 0.f, 0.f};
  float l = 0.f;
  for (int s = 0; s < S; ++s) {
    h += *(const f32x4*)(acc_part + ((size_t)s * N_ROWS + row) * F_OUT + 4 * f4);
    l += l_part[(size_t)s * N_ROWS + row];
  }
  const float inv = 1.0f / l;
  f32x4 o;
  {
    float v0 = h.x * inv; o.x = v0 > 0.f ? v0 : (__expf(v0) - 1.0f);
    float v1 = h.y * inv; o.y = v1 > 0.f ? v1 : (__expf(v1) - 1.0f);
    float v2 = h.z * inv; o.z = v2 > 0.f ? v2 : (__expf(v2) - 1.0f);
    float v3 = h.w * inv; o.w = v3 > 0.f ? v3 : (__expf(v3) - 1.0f);
  }
  *(f32x4*)(out + (size_t)row * F_OUT + 4 * f4) = o;
}

// ---------------- launch ----------------
extern "C" void kernel_launch(void* const* d_in, const int* in_sizes, int n_in,
                              void* d_out, int out_size, void* d_ws, size_t ws_size,
                              hipStream_t stream) {
  const float* x   = (const float*)d_in[0];
  const int*   adj = (const int*)d_in[1];
  const float* w   = (const float*)d_in[2];
  const float* a   = (const float*)d_in[3];
  float* out = (float*)d_out;
  char* ws = (char*)d_ws;

  short* whT      = (short*)(ws + OFF_WHT);
  float* src      = (float*)(ws + OFF_SRC);
  float* dst      = (float*)(ws + OFF_DST);
  float* dmax     = (float*)(ws + OFF_DMAX);
  float* l_part   = (float*)(ws + OFF_LP);
  float* acc_part = (float*)(ws + OFF_ACC);

  // j-split count chosen from available workspace (deterministic)
  int S = 1;
  if (ws_size >= OFF_ACC + 4ull * 2097152) S = 4;
  else if (ws_size >= OFF_ACC + 2ull * 2097152) S = 2;

  k1_proj<<<N_ROWS / 32, 256, 0, stream>>>(x, w, a, whT, src, dst);
  k1b_dstmax<<<1, 256, 0, stream>>>(dst, dmax);
  k2_attn<<<dim3(N_ROWS / BR, S), 256, 0, stream>>>(adj, whT, src, dst, dmax,
                                                    acc_part, l_part, S);
  k3_combine<<<(N_ROWS * F_OUT / 4) / 256, 256, 0, stream>>>(acc_part, l_part, out, S);
}

// Round 3
// 120.301 us; speedup vs baseline: 2.9487x; 1.0332x over previous
//
#include <hip/hip_runtime.h>

// GraphAttentionLayer: out = elu( softmax_row( where(adj>0, lrelu(src_i+dst_j), 0) ) @ wh )
// wh = x@w [8192,64]; src = wh@a[:64]; dst = wh@a[64:]
//
// R2 analysis: k2_attn ~105us vs 43us adj-read floor (2.6 TB/s) — latency-bound:
// 2 barriers/tile, serial load->VALU->MFMA chain, 4 blocks/CU.
// R3 changes:
//  - m = 0 shift (exact: softmax shift-invariant; e<=~6 so exp<=~400, fp32-safe).
//    Removes k1b_dstmax + dependency.
//  - Double-buffered P tile in LDS, XOR swizzle (byte ^= (row&15)<<4, stride 512B)
//    -> 32KB LDS, 5 blocks/CU, ONE barrier per tile.
//  - Register prefetch of next tile's adj+dst during sync+MFMA phase.
//  - S=8 j-splits (templated, NT=4 static unroll), 2048 blocks.
//  - Non-temporal adj loads / partial stores (keep whT hot in L2).

constexpr int N_ROWS = 8192;
constexpr int F_IN   = 128;
constexpr int F_OUT  = 64;
#define LRELU_A 0.2f

constexpr int BR   = 32;       // rows per block in attention kernel
constexpr int BC   = 256;      // j-columns per tile
constexpr int ROWB = BC * 2;   // LDS row stride in bytes (512)

// workspace layout (bytes)
constexpr size_t OFF_WHT  = 0;                    // 64*8192*2 = 1 MiB bf16 [f][row]
constexpr size_t OFF_SRC  = 1048576;              // 8192 f32
constexpr size_t OFF_DST  = OFF_SRC + 32768;      // 8192 f32
constexpr size_t OFF_LP   = OFF_DST + 32768;      // S*8192 f32 (S<=8)
constexpr size_t OFF_ACC  = OFF_LP + 8 * 32768;   // S*8192*64 f32

typedef __attribute__((ext_vector_type(4))) float f32x4;
typedef __attribute__((ext_vector_type(4))) int   i32x4;
typedef __attribute__((ext_vector_type(4))) short s16x4;
typedef __attribute__((ext_vector_type(8))) short s16x8;

static __device__ __forceinline__ short f2bf(float f) {
  unsigned u = __float_as_uint(f);
  u = (u + 0x7fffu + ((u >> 16) & 1u)) >> 16;  // RNE, no NaN inputs here
  return (short)u;
}

// ---------------- Kernel 1: wh = x@w ; src/dst ; whT (bf16) ----------------
__global__ __launch_bounds__(256) void k1_proj(
    const float* __restrict__ x, const float* __restrict__ w,
    const float* __restrict__ a, short* __restrict__ whT,
    float* __restrict__ src, float* __restrict__ dst)
{
  const int lane = threadIdx.x & 63;   // = output feature f
  const int wid  = threadIdx.x >> 6;
  const int rowBase = blockIdx.x * 32 + wid * 8;   // 8 rows per wave

  float acc[8];
#pragma unroll
  for (int r = 0; r < 8; ++r) acc[r] = 0.0f;

#pragma unroll 1
  for (int kc = 0; kc < 4; ++kc) {     // K chunks of 32 — keep ONE wreg live
    float wreg[32];
#pragma unroll
    for (int kk = 0; kk < 32; ++kk)
      wreg[kk] = w[(kc * 32 + kk) * F_OUT + lane];   // coalesced
#pragma unroll
    for (int r = 0; r < 8; ++r) {
      const f32x4* xp = (const f32x4*)(x + (size_t)(rowBase + r) * F_IN + kc * 32);
#pragma unroll
      for (int q = 0; q < 8; ++q) {    // wave-uniform broadcast loads
        f32x4 xv = xp[q];
        acc[r] = fmaf(xv.x, wreg[4*q+0], acc[r]);
        acc[r] = fmaf(xv.y, wreg[4*q+1], acc[r]);
        acc[r] = fmaf(xv.z, wreg[4*q+2], acc[r]);
        acc[r] = fmaf(xv.w, wreg[4*q+3], acc[r]);
      }
    }
  }

  // whT store: lane f's 8 consecutive rows -> one 16B packed store
  s16x8 hb;
#pragma unroll
  for (int r = 0; r < 8; ++r) hb[r] = f2bf(acc[r]);
  *(s16x8*)&whT[(size_t)lane * N_ROWS + rowBase] = hb;

  const float aS = a[lane];
  const float aD = a[F_OUT + lane];
#pragma unroll
  for (int r = 0; r < 8; ++r) {
    float ts = acc[r] * aS;
    float td = acc[r] * aD;
#pragma unroll
    for (int off = 32; off > 0; off >>= 1) {
      ts += __shfl_xor(ts, off, 64);
      td += __shfl_xor(td, off, 64);
    }
    if (lane == 0) { src[rowBase + r] = ts; dst[rowBase + r] = td; }
  }
}

// ---------------- Kernel 2: fused mask+softmax-numerator+PV ----------------
// grid: (N/BR, S), 256 threads (4 waves). One barrier per tile, double-buffered P.
template<int S>
__global__ __launch_bounds__(256) void k2_attn(
    const int* __restrict__ adj, const short* __restrict__ whT,
    const float* __restrict__ src, const float* __restrict__ dst,
    float* __restrict__ acc_part, float* __restrict__ l_part)
{
  constexpr int JLEN = N_ROWS / S;
  constexpr int NT   = JLEN / BC;
  __shared__ short Plds[2][BR * BC];   // swizzled, 2 x 16KB

  const int lane = threadIdx.x & 63;
  const int wid  = threadIdx.x >> 6;
  const int rb   = blockIdx.x;
  const int s    = blockIdx.y;
  const int jbase = s * JLEN;
  const int rowg  = rb * BR + wid * 8;   // this wave's first phase-A row

  float srcv[8], lp[8];
#pragma unroll
  for (int r = 0; r < 8; ++r) {
    srcv[r] = src[rowg + r];
    lp[r]   = 0.0f;
  }

  // MFMA tile ownership: Mtile = wid&1, Ntiles = (wid>>1)*2 + {0,1}
  const int mt  = wid & 1;
  const int nt0 = (wid >> 1) * 2;
  f32x4 accA = {0.f, 0.f, 0.f, 0.f};
  f32x4 accB = {0.f, 0.f, 0.f, 0.f};

  // prefetch registers (tile t's adj + dst)
  i32x4 av[8];
  f32x4 d4;
  {
    d4 = *(const f32x4*)(dst + jbase + 4 * lane);
#pragma unroll
    for (int r = 0; r < 8; ++r)
      av[r] = __builtin_nontemporal_load(
          (const i32x4*)(adj + (size_t)(rowg + r) * N_ROWS + jbase + 4 * lane));
  }

#pragma unroll 2
  for (int t = 0; t < NT; ++t) {
    const int j0 = jbase + t * BC;

    // ---- phase A: p = exp(masked lrelu(src+dst)), pack bf16 -> Plds[t&1] ----
#pragma unroll
    for (int r = 0; r < 8; ++r) {
      const i32x4 avv = av[r];
      const float sv = srcv[r];
      float e0 = sv + d4.x; e0 = fmaxf(e0, LRELU_A * e0); e0 = avv.x > 0 ? e0 : 0.f;
      float e1 = sv + d4.y; e1 = fmaxf(e1, LRELU_A * e1); e1 = avv.y > 0 ? e1 : 0.f;
      float e2 = sv + d4.z; e2 = fmaxf(e2, LRELU_A * e2); e2 = avv.z > 0 ? e2 : 0.f;
      float e3 = sv + d4.w; e3 = fmaxf(e3, LRELU_A * e3); e3 = avv.w > 0 ? e3 : 0.f;
      const float p0 = __expf(e0);
      const float p1 = __expf(e1);
      const float p2 = __expf(e2);
      const float p3 = __expf(e3);
      lp[r] += (p0 + p1) + (p2 + p3);
      s16x4 pk; pk.x = f2bf(p0); pk.y = f2bf(p1); pk.z = f2bf(p2); pk.w = f2bf(p3);
      const int rl = wid * 8 + r;
      const int wb = rl * ROWB + ((lane * 8) ^ ((rl & 15) << 4));
      *(s16x4*)((char*)&Plds[t & 1][0] + wb) = pk;
    }

    // ---- prefetch tile t+1 (overlaps barrier + MFMA below) ----
    if (t + 1 < NT) {
      const int j1 = j0 + BC;
      d4 = *(const f32x4*)(dst + j1 + 4 * lane);
#pragma unroll
      for (int r = 0; r < 8; ++r)
        av[r] = __builtin_nontemporal_load(
            (const i32x4*)(adj + (size_t)(rowg + r) * N_ROWS + j1 + 4 * lane));
    }

    __syncthreads();   // P(t) visible; also guarantees MFMA(t-1) reads done

    // ---- phase B: PV MFMA from Plds[t&1] + whT (L2) ----
    const int arow = mt * 16 + (lane & 15);
    const char* abase = (const char*)&Plds[t & 1][0] + arow * ROWB;
    const int aswz = (arow & 15) << 4;
    const short* bp = whT + (size_t)(nt0 * 16 + (lane & 15)) * N_ROWS
                      + j0 + (lane >> 4) * 8;
#pragma unroll
    for (int k = 0; k < BC / 32; ++k) {
      const s16x8 afr = *(const s16x8*)(abase + ((k * 64 + (lane >> 4) * 16) ^ aswz));
      const s16x8 bf0 = *(const s16x8*)(bp + k * 32);
      const s16x8 bf1 = *(const s16x8*)(bp + k * 32 + (size_t)16 * N_ROWS);
      accA = __builtin_amdgcn_mfma_f32_16x16x32_bf16(afr, bf0, accA, 0, 0, 0);
      accB = __builtin_amdgcn_mfma_f32_16x16x32_bf16(afr, bf1, accB, 0, 0, 0);
    }
    // no second barrier: next phase-A writes buffer (t+1)&1, which every wave
    // finished reading (MFMA(t-1)) before it could have passed sync(t).
  }

  // ---- epilogue: row-sum partials + accumulator store ----
#pragma unroll
  for (int r = 0; r < 8; ++r) {
    float v = lp[r];
#pragma unroll
    for (int off = 32; off > 0; off >>= 1) v += __shfl_xor(v, off, 64);
    if (lane == 0) l_part[(size_t)s * N_ROWS + rowg + r] = v;
  }
#pragma unroll
  for (int rg = 0; rg < 4; ++rg) {
    // verified C/D layout: col = lane&15, row = (lane>>4)*4 + reg
    const int row = rb * BR + mt * 16 + (lane >> 4) * 4 + rg;
    const int f0  = nt0 * 16 + (lane & 15);
    __builtin_nontemporal_store(accA[rg],
        acc_part + ((size_t)s * N_ROWS + row) * F_OUT + f0);
    __builtin_nontemporal_store(accB[rg],
        acc_part + ((size_t)s * N_ROWS + row) * F_OUT + f0 + 16);
  }
}

// ---------------- Kernel 3: combine partials, normalize, ELU ----------------
template<int S>
__global__ __launch_bounds__(256) void k3_combine(
    const float* __restrict__ acc_part, const float* __restrict__ l_part,
    float* __restrict__ out)
{
  const int idx = blockIdx.x * 256 + threadIdx.x;  // over N*F/4
  const int row = idx >> 4;          // F_OUT/4 = 16
  const int f4  = idx & 15;
  f32x4 h = {0.f, 0.f, 0.f, 0.f};
  float l = 0.f;
#pragma unroll
  for (int s = 0; s < S; ++s) {
    h += *(const f32x4*)(acc_part + ((size_t)s * N_ROWS + row) * F_OUT + 4 * f4);
    l += l_part[(size_t)s * N_ROWS + row];
  }
  const float inv = 1.0f / l;
  f32x4 o;
  {
    float v0 = h.x * inv; o.x = v0 > 0.f ? v0 : (__expf(v0) - 1.0f);
    float v1 = h.y * inv; o.y = v1 > 0.f ? v1 : (__expf(v1) - 1.0f);
    float v2 = h.z * inv; o.z = v2 > 0.f ? v2 : (__expf(v2) - 1.0f);
    float v3 = h.w * inv; o.w = v3 > 0.f ? v3 : (__expf(v3) - 1.0f);
  }
  *(f32x4*)(out + (size_t)row * F_OUT + 4 * f4) = o;
}

// ---------------- launch ----------------
extern "C" void kernel_launch(void* const* d_in, const int* in_sizes, int n_in,
                              void* d_out, int out_size, void* d_ws, size_t ws_size,
                              hipStream_t stream) {
  const float* x   = (const float*)d_in[0];
  const int*   adj = (const int*)d_in[1];
  const float* w   = (const float*)d_in[2];
  const float* a   = (const float*)d_in[3];
  float* out = (float*)d_out;
  char* ws = (char*)d_ws;

  short* whT      = (short*)(ws + OFF_WHT);
  float* src      = (float*)(ws + OFF_SRC);
  float* dst      = (float*)(ws + OFF_DST);
  float* l_part   = (float*)(ws + OFF_LP);
  float* acc_part = (float*)(ws + OFF_ACC);

  k1_proj<<<N_ROWS / 32, 256, 0, stream>>>(x, w, a, whT, src, dst);

  if (ws_size >= OFF_ACC + 8ull * N_ROWS * F_OUT * 4) {
    k2_attn<8><<<dim3(N_ROWS / BR, 8), 256, 0, stream>>>(adj, whT, src, dst,
                                                         acc_part, l_part);
    k3_combine<8><<<(N_ROWS * F_OUT / 4) / 256, 256, 0, stream>>>(acc_part, l_part, out);
  } else {
    k2_attn<2><<<dim3(N_ROWS / BR, 2), 256, 0, stream>>>(adj, whT, src, dst,
                                                         acc_part, l_part);
    k3_combine<2><<<(N_ROWS * F_OUT / 4) / 256, 256, 0, stream>>>(acc_part, l_part, out);
  }
}